// Round 5
// baseline (51.868 us; speedup 1.0000x reference)
//
#include <hip/hip_runtime.h>
#include <hip/hip_bf16.h>

#define M_DIM 4096
#define N_DIM 8192
#define D_DIM 256
#define NSLICE 32                    /* 256-col slices of N */
#define C_EXP (-0.7213475204444817f) /* -1/(2 ln2): exp(-d/2) = 2^(d*C_EXP) */
#define K_ACC (1.4426950408889634f)  /* -2*C_EXP: acc coefficient */
#define SKIP_THR (-151.0f)           /* exp2f(x)==0.0f exactly for x<=-151 */

typedef __attribute__((ext_vector_type(8))) short short8; // 8 bf16 = 4 VGPR
typedef __attribute__((ext_vector_type(4))) float f32x4;  // MFMA C/D frag

__device__ inline unsigned short f2bf(float f) {
    __hip_bfloat16 h = __float2bfloat16(f);
    return *reinterpret_cast<unsigned short*>(&h);
}

// ---------------------------------------------------------------------------
// prep: fp32 -> bf16 rows for X and X_train; per-row sum-of-squares PRE-SCALED
// by -1/(2 ln2). One wave per row (64 lanes x float4 = 256 elems).
// ---------------------------------------------------------------------------
__global__ __launch_bounds__(256) void prep_kernel(
    const float* __restrict__ X, const float* __restrict__ T,
    unsigned short* __restrict__ Xb, unsigned short* __restrict__ Tb,
    float* __restrict__ sq1, float* __restrict__ sq2)
{
    const int row  = blockIdx.x * 4 + (threadIdx.x >> 6);
    const int lane = threadIdx.x & 63;
    const float* src; unsigned short* dst; float* sqp; int r;
    if (row < M_DIM) { src = X; dst = Xb; sqp = sq1; r = row; }
    else             { src = T; dst = Tb; sqp = sq2; r = row - M_DIM; }

    const float4* s4 = reinterpret_cast<const float4*>(src + (size_t)r * D_DIM);
    float4 v = s4[lane];
    float ss = v.x * v.x + v.y * v.y + v.z * v.z + v.w * v.w;

    ushort4 b4;
    b4.x = f2bf(v.x); b4.y = f2bf(v.y); b4.z = f2bf(v.z); b4.w = f2bf(v.w);
    reinterpret_cast<ushort4*>(dst + (size_t)r * D_DIM)[lane] = b4;

    #pragma unroll
    for (int o = 1; o < 64; o <<= 1) ss += __shfl_xor(ss, o);
    if (lane == 0) sqp[r] = ss * C_EXP;
}

// ---------------------------------------------------------------------------
// Barrier-free fused RBF GEMM. Wave-independent: each wave owns 64 A-rows
// (full K=256 resident in 128 VGPRs as MFMA fragments) x one 256-col slice.
// B streamed L2->registers per 16-col chunk (no LDS, no barriers, no vmcnt
// drains, no atomics). Per chunk: 8 dwordx4 B-loads, 32 MFMA (4 m-tiles x
// 8 k-steps), then exp2/alpha epilogue with an EXACT underflow fast-path
// (skip when all args <= -151: exp2f == 0.0f). Partials to part[cslice][M].
// blockIdx&31 = cslice -> XCD x reads only B-slices {x,x+8,x+16,x+24}
// (512 KB, L2-resident).
// MFMA frag layouts (m89/m91-verified): A/B lane l: row/col=l&15, k-elems
// (l>>4)*8..+7 per 32-k window; C/D: col=lane&15, row=(lane>>4)*4+reg.
// ---------------------------------------------------------------------------
__global__ __launch_bounds__(256, 2) void gemm_kernel(
    const unsigned short* __restrict__ Xb, const unsigned short* __restrict__ Tb,
    const float* __restrict__ sq1, const float* __restrict__ sq2,
    const float* __restrict__ alpha, float* __restrict__ part)
{
    const int cslice = blockIdx.x & 31;          // XCD-pinned B slice
    const int quad   = blockIdx.x >> 5;          // 0..15: 256-row group
    const int wid    = threadIdx.x >> 6;
    const int lane   = threadIdx.x & 63;
    const int l15    = lane & 15;
    const int lg     = lane >> 4;

    const int rowbase = quad * 256 + wid * 64;   // this wave's 64 rows
    const int colbase = cslice * 256;            // this wave's 256 cols

    // ---- A fragments: 64 rows x full K in registers (32 x dwordx4) ----
    short8 af[4][8];
    #pragma unroll
    for (int m = 0; m < 4; ++m)
        #pragma unroll
        for (int ks = 0; ks < 8; ++ks)
            af[m][ks] = *(const short8*)(Xb +
                (size_t)(rowbase + m * 16 + l15) * D_DIM + ks * 32 + lg * 8);

    // ---- sq1 for this lane's 16 (m,r) rows: row = m*16 + lg*4 + r ----
    float4 s1v[4];
    #pragma unroll
    for (int m = 0; m < 4; ++m)
        s1v[m] = *reinterpret_cast<const float4*>(sq1 + rowbase + m * 16 + lg * 4);

    float psum[4][4];
    #pragma unroll
    for (int m = 0; m < 4; ++m)
        #pragma unroll
        for (int r = 0; r < 4; ++r) psum[m][r] = 0.0f;

    // ---- stream B: 16 chunks of 16 cols ----
    #pragma unroll 2
    for (int c = 0; c < 16; ++c) {
        const int col = colbase + c * 16 + l15;
        short8 bf[8];
        #pragma unroll
        for (int ks = 0; ks < 8; ++ks)
            bf[ks] = *(const short8*)(Tb +
                (size_t)col * D_DIM + ks * 32 + lg * 8);
        const float s2c = sq2[col];    // pre-scaled by C_EXP
        const float alf = alpha[col];

        f32x4 acc[4];
        #pragma unroll
        for (int m = 0; m < 4; ++m) acc[m] = (f32x4)0.0f;
        #pragma unroll
        for (int ks = 0; ks < 8; ++ks)
            #pragma unroll
            for (int m = 0; m < 4; ++m)
                acc[m] = __builtin_amdgcn_mfma_f32_16x16x32_bf16(
                    af[m][ks], bf[ks], acc[m], 0, 0, 0);

        // epilogue: arg = C_EXP*(d^2) ; exact-zero fast path
        float arg[4][4], mx = -1e30f;
        #pragma unroll
        for (int m = 0; m < 4; ++m)
            #pragma unroll
            for (int r = 0; r < 4; ++r) {
                arg[m][r] = fmaf(acc[m][r], K_ACC, s1v[m][r] + s2c);
                mx = fmaxf(mx, arg[m][r]);
            }
        if (!__all(mx < SKIP_THR)) {
            #pragma unroll
            for (int m = 0; m < 4; ++m)
                #pragma unroll
                for (int r = 0; r < 4; ++r)
                    psum[m][r] = fmaf(__builtin_amdgcn_exp2f(arg[m][r]), alf,
                                      psum[m][r]);
        }
    }

    // ---- reduce over the 16 l15-lanes (cols) and store partials ----
    #pragma unroll
    for (int m = 0; m < 4; ++m) {
        float4 pv;
        #pragma unroll
        for (int r = 0; r < 4; ++r) {
            float p = psum[m][r];
            p += __shfl_xor(p, 1);
            p += __shfl_xor(p, 2);
            p += __shfl_xor(p, 4);
            p += __shfl_xor(p, 8);
            ((float*)&pv)[r] = p;
        }
        if (l15 == 0) // 4 lanes (lg=0..3) write 4 consecutive floats each
            *reinterpret_cast<float4*>(part + (size_t)cslice * M_DIM +
                                       rowbase + m * 16 + lg * 4) = pv;
    }
}

// ---------------------------------------------------------------------------
// reduce: out[i] = sum over 32 col-slices of part[cs][i]. 16 blocks x 256.
// ---------------------------------------------------------------------------
__global__ __launch_bounds__(256) void reduce_kernel(
    const float* __restrict__ part, float* __restrict__ out)
{
    const int gi = blockIdx.x * 256 + threadIdx.x;
    float s = 0.0f;
    #pragma unroll
    for (int b = 0; b < NSLICE; ++b) s += part[(size_t)b * M_DIM + gi];
    out[gi] = s;
}

extern "C" void kernel_launch(void* const* d_in, const int* in_sizes, int n_in,
                              void* d_out, int out_size, void* d_ws, size_t ws_size,
                              hipStream_t stream)
{
    const float* X  = (const float*)d_in[0];
    const float* T  = (const float*)d_in[1];
    const float* al = (const float*)d_in[2];
    float* out = (float*)d_out;

    char* ws = (char*)d_ws;
    unsigned short* Xb = (unsigned short*)ws;                               // 2 MiB
    unsigned short* Tb = (unsigned short*)(ws + (size_t)M_DIM * D_DIM * 2); // 4 MiB
    float* sq1 = (float*)(ws + (size_t)(M_DIM + N_DIM) * D_DIM * 2);        // 16 KiB
    float* sq2 = sq1 + M_DIM;                                               // 32 KiB
    float* part = sq2 + N_DIM;                                              // 512 KiB

    prep_kernel<<<(M_DIM + N_DIM) / 4, 256, 0, stream>>>(X, T, Xb, Tb, sq1, sq2);
    gemm_kernel<<<16 * NSLICE, 256, 0, stream>>>(Xb, Tb, sq1, sq2, al, part);
    reduce_kernel<<<M_DIM / 256, 256, 0, stream>>>(part, out);
}

// Round 6
// 37.439 us; speedup vs baseline: 1.3854x; 1.3854x over previous
//
#include <hip/hip_runtime.h>
#include <hip/hip_bf16.h>

#define M_DIM 4096
#define N_DIM 8192
#define D_DIM 256
#define NSLICE 32                    /* 256-col slices of N */
#define NCHUNK 16                    /* 16-col chunks per slice */
#define C_EXP (-0.7213475204444817f) /* -1/(2 ln2): exp(-d/2) = 2^(d*C_EXP) */
#define K_ACC (1.4426950408889634f)  /* -2*C_EXP: acc coefficient */
#define SKIP_THR (-151.0f)           /* exp2f(x)==0.0f exactly for x<=-151 */
/* wave-private LDS: [bufB0 8K][bufB1 8K][bufS0 1K][bufS1 1K] = 18 KiB */
#define WLDS 18432

typedef __attribute__((ext_vector_type(8))) short short8; // 8 bf16 = 4 VGPR
typedef __attribute__((ext_vector_type(4))) float f32x4;  // MFMA C/D frag

__device__ inline unsigned short f2bf(float f) {
    __hip_bfloat16 h = __float2bfloat16(f);
    return *reinterpret_cast<unsigned short*>(&h);
}

// ---------------------------------------------------------------------------
// prep: fp32 -> bf16 rows; for X rows also sq1[r] = ||x||^2 * C_EXP; for
// X_train rows sqal[r] = {||t||^2 * C_EXP, alpha[r]} (packed so the gemm
// loop has NO loose global loads -> exact vmcnt counting).
// ---------------------------------------------------------------------------
__global__ __launch_bounds__(256) void prep_kernel(
    const float* __restrict__ X, const float* __restrict__ T,
    const float* __restrict__ alpha,
    unsigned short* __restrict__ Xb, unsigned short* __restrict__ Tb,
    float* __restrict__ sq1, float2* __restrict__ sqal)
{
    const int row  = blockIdx.x * 4 + (threadIdx.x >> 6);
    const int lane = threadIdx.x & 63;
    const float* src; unsigned short* dst; int r; bool isX;
    if (row < M_DIM) { src = X; dst = Xb; r = row; isX = true; }
    else             { src = T; dst = Tb; r = row - M_DIM; isX = false; }

    const float4* s4 = reinterpret_cast<const float4*>(src + (size_t)r * D_DIM);
    float4 v = s4[lane];
    float ss = v.x * v.x + v.y * v.y + v.z * v.z + v.w * v.w;

    ushort4 b4;
    b4.x = f2bf(v.x); b4.y = f2bf(v.y); b4.z = f2bf(v.z); b4.w = f2bf(v.w);
    reinterpret_cast<ushort4*>(dst + (size_t)r * D_DIM)[lane] = b4;

    #pragma unroll
    for (int o = 1; o < 64; o <<= 1) ss += __shfl_xor(ss, o);
    if (lane == 0) {
        if (isX) sq1[r] = ss * C_EXP;
        else     sqal[r] = make_float2(ss * C_EXP, alpha[r]);
    }
}

// ---------------------------------------------------------------------------
// Barrier-free fused RBF GEMM. Wave = 64 A-rows (full K=256 in 128 VGPRs)
// x one 256-col slice. B streamed 16-cols-at-a-time through wave-PRIVATE
// double-buffered LDS via global_load_lds (no __syncthreads anywhere).
// Counted pipeline per iter: stage(i+1) [9 loads] -> s_waitcnt vmcnt(9)
// -> ds_read/MFMA on buf i&1. stage never writes the buffer being read.
// Loop contains no other VMEM (sqal staged with the chunk) so counts are
// exact. LDS slot swizzle s' = s ^ (col&7) on both sides (G21).
// MFMA frag layouts (m89/m91): A/B lane l: row/col=l&15, k=(l>>4)*8..+7
// per 32-k window; C/D: col=lane&15, row=(lane>>4)*4+reg.
// blockIdx&31 = cslice -> XCD-pinned B slices, L2-resident.
// ---------------------------------------------------------------------------
__global__ __launch_bounds__(256, 2) void gemm_kernel(
    const unsigned short* __restrict__ Xb, const unsigned short* __restrict__ Tb,
    const float* __restrict__ sq1, const float2* __restrict__ sqal,
    float* __restrict__ part)
{
    __shared__ __align__(16) char smem[4 * WLDS]; // 72 KiB
    const int cslice = blockIdx.x & 31;
    const int quad   = blockIdx.x >> 5;
    const int wid    = threadIdx.x >> 6;
    const int lane   = threadIdx.x & 63;
    const int l15    = lane & 15;
    const int lg     = lane >> 4;

    char* wlds = smem + wid * WLDS;
    const int rowbase = quad * 256 + wid * 64;
    const int colbase = cslice * 256;

    // ---- A fragments: 64 rows x full K in registers (32 x dwordx4) ----
    short8 af[4][8];
    #pragma unroll
    for (int m = 0; m < 4; ++m)
        #pragma unroll
        for (int ks = 0; ks < 8; ++ks)
            af[m][ks] = *(const short8*)(Xb +
                (size_t)(rowbase + m * 16 + l15) * D_DIM + ks * 32 + lg * 8);

    float4 s1v[4];
    #pragma unroll
    for (int m = 0; m < 4; ++m)
        s1v[m] = *reinterpret_cast<const float4*>(sq1 + rowbase + m * 16 + lg * 4);
    float s1max = -1e30f;
    #pragma unroll
    for (int m = 0; m < 4; ++m)
        #pragma unroll
        for (int r = 0; r < 4; ++r) s1max = fmaxf(s1max, s1v[m][r]);

    // Fence: pin all plain global loads OLDER than the first stage op so
    // the in-loop vmcnt counts are exact.
    asm volatile("s_waitcnt vmcnt(0)" ::: "memory");

    const char* TbB = (const char*)Tb;
    const char* SaB = (const char*)sqal;

    // stage chunk i into buffer i&1: 8 B-loads + 1 sqal-load = 9 vmcnt ops
    auto stage = [&](int i) {
        const int b = i & 1;
        char* bufB = wlds + b * 8192;
        #pragma unroll
        for (int j = 0; j < 8; ++j) {
            const int col_local = j * 2 + (lane >> 5);
            const size_t src = (size_t)(colbase + i * 16 + col_local) * 512
                             + (size_t)(((lane & 31) ^ (col_local & 7)) * 16);
            __builtin_amdgcn_global_load_lds(
                (const __attribute__((address_space(1))) void*)(TbB + src),
                (__attribute__((address_space(3))) void*)(bufB + j * 1024), 16, 0, 0);
        }
        const size_t ssrc = (size_t)(colbase + i * 16) * 8 + (lane & 7) * 16;
        __builtin_amdgcn_global_load_lds(
            (const __attribute__((address_space(1))) void*)(SaB + ssrc),
            (__attribute__((address_space(3))) void*)(wlds + 16384 + b * 1024), 16, 0, 0);
    };

    float psum[4][4];
    #pragma unroll
    for (int m = 0; m < 4; ++m)
        #pragma unroll
        for (int r = 0; r < 4; ++r) psum[m][r] = 0.0f;

    // compute chunk i from buffer i&1
    auto compute = [&](int i) {
        const int b = i & 1;
        const char* bufB = wlds + b * 8192;
        f32x4 acc[4];
        #pragma unroll
        for (int m = 0; m < 4; ++m) acc[m] = (f32x4)0.0f;
        #pragma unroll
        for (int ks = 0; ks < 8; ++ks) {
            const short8 bf = *(const short8*)(bufB + l15 * 512 +
                (((ks * 4 + lg) ^ (l15 & 7)) * 16));
            #pragma unroll
            for (int m = 0; m < 4; ++m)
                acc[m] = __builtin_amdgcn_mfma_f32_16x16x32_bf16(
                    af[m][ks], bf, acc[m], 0, 0, 0);
        }
        const float2 sa = *(const float2*)(wlds + 16384 + b * 1024 + l15 * 8);
        // cheap monotone upper bound on all 16 args (K_ACC > 0)
        float amax = acc[0][0];
        #pragma unroll
        for (int m = 0; m < 4; ++m)
            #pragma unroll
            for (int r = 0; r < 4; ++r) amax = fmaxf(amax, acc[m][r]);
        const float bound = fmaf(amax, K_ACC, s1max + sa.x);
        if (!__all(bound < SKIP_THR)) {
            #pragma unroll
            for (int m = 0; m < 4; ++m)
                #pragma unroll
                for (int r = 0; r < 4; ++r) {
                    const float arg = fmaf(acc[m][r], K_ACC, s1v[m][r] + sa.x);
                    psum[m][r] = fmaf(__builtin_amdgcn_exp2f(arg), sa.y, psum[m][r]);
                }
        }
    };

    stage(0);
    #pragma unroll 1
    for (int i = 0; i < NCHUNK - 1; ++i) {
        stage(i + 1);                                    // 9 ops, buf (i+1)&1
        asm volatile("s_waitcnt vmcnt(9)" ::: "memory"); // chunk i landed
        compute(i);
    }
    asm volatile("s_waitcnt vmcnt(0)" ::: "memory");
    compute(NCHUNK - 1);

    // ---- reduce over the 16 l15-lanes (cols) and store partials ----
    #pragma unroll
    for (int m = 0; m < 4; ++m) {
        float4 pv;
        #pragma unroll
        for (int r = 0; r < 4; ++r) {
            float p = psum[m][r];
            p += __shfl_xor(p, 1);
            p += __shfl_xor(p, 2);
            p += __shfl_xor(p, 4);
            p += __shfl_xor(p, 8);
            ((float*)&pv)[r] = p;
        }
        if (l15 == 0) // 4 lanes (lg=0..3) write 4 consecutive floats each
            *reinterpret_cast<float4*>(part + (size_t)cslice * M_DIM +
                                       rowbase + m * 16 + lg * 4) = pv;
    }
}

// ---------------------------------------------------------------------------
// reduce: out[i] = sum over 32 col-slices of part[cs][i]. 16 blocks x 256.
// ---------------------------------------------------------------------------
__global__ __launch_bounds__(256) void reduce_kernel(
    const float* __restrict__ part, float* __restrict__ out)
{
    const int gi = blockIdx.x * 256 + threadIdx.x;
    float s = 0.0f;
    #pragma unroll
    for (int b = 0; b < NSLICE; ++b) s += part[(size_t)b * M_DIM + gi];
    out[gi] = s;
}

extern "C" void kernel_launch(void* const* d_in, const int* in_sizes, int n_in,
                              void* d_out, int out_size, void* d_ws, size_t ws_size,
                              hipStream_t stream)
{
    const float* X  = (const float*)d_in[0];
    const float* T  = (const float*)d_in[1];
    const float* al = (const float*)d_in[2];
    float* out = (float*)d_out;

    char* ws = (char*)d_ws;
    unsigned short* Xb = (unsigned short*)ws;                               // 2 MiB
    unsigned short* Tb = (unsigned short*)(ws + (size_t)M_DIM * D_DIM * 2); // 4 MiB
    float* sq1  = (float*)(ws + (size_t)(M_DIM + N_DIM) * D_DIM * 2);       // 16 KiB
    float2* sqal = (float2*)(sq1 + M_DIM);                                  // 64 KiB
    float* part = (float*)(sqal + N_DIM);                                   // 512 KiB

    prep_kernel<<<(M_DIM + N_DIM) / 4, 256, 0, stream>>>(X, T, al, Xb, Tb, sq1, sqal);
    gemm_kernel<<<16 * NSLICE, 256, 0, stream>>>(Xb, Tb, sq1, sqal, part);
    reduce_kernel<<<M_DIM / 256, 256, 0, stream>>>(part, out);
}

// Round 7
// 34.450 us; speedup vs baseline: 1.5056x; 1.0868x over previous
//
#include <hip/hip_runtime.h>
#include <hip/hip_bf16.h>

#define M_DIM 4096
#define N_DIM 8192
#define D_DIM 256
#define NSLICE 32                    /* 256-col slices of N */
#define NCHUNK 16                    /* 16-col chunks per slice */
#define C_EXP (-0.7213475204444817f) /* -1/(2 ln2): exp(-d/2) = 2^(d*C_EXP) */
#define K_ACC (1.4426950408889634f)  /* -2*C_EXP: acc coefficient */
#define SKIP_THR (-151.0f)           /* exp2f(x)==0.0f exactly for x<=-151 */
#define BUFB 8192                    /* one 16-col B chunk: 16 x 512 B */
#define SQAL_OFF (4 * BUFB)          /* sqal slice: 256 x 8 B = 2 KB */
#define LDS_BYTES (4 * BUFB + 2048)  /* 34 KiB -> 2 blocks/CU */

typedef __attribute__((ext_vector_type(8))) short short8; // 8 bf16 = 4 VGPR
typedef __attribute__((ext_vector_type(4))) float f32x4;  // MFMA C/D frag

__device__ inline unsigned short f2bf(float f) {
    __hip_bfloat16 h = __float2bfloat16(f);
    return *reinterpret_cast<unsigned short*>(&h);
}

// ---------------------------------------------------------------------------
// prep: fp32 -> bf16 rows; X rows: sq1[r] = ||x||^2 * C_EXP; X_train rows:
// sqal[r] = {||t||^2 * C_EXP, alpha[r]} (packed: gemm loop has no loose
// global loads -> exact vmcnt counting).
// ---------------------------------------------------------------------------
__global__ __launch_bounds__(256) void prep_kernel(
    const float* __restrict__ X, const float* __restrict__ T,
    const float* __restrict__ alpha,
    unsigned short* __restrict__ Xb, unsigned short* __restrict__ Tb,
    float* __restrict__ sq1, float2* __restrict__ sqal)
{
    const int row  = blockIdx.x * 4 + (threadIdx.x >> 6);
    const int lane = threadIdx.x & 63;
    const float* src; unsigned short* dst; int r; bool isX;
    if (row < M_DIM) { src = X; dst = Xb; r = row; isX = true; }
    else             { src = T; dst = Tb; r = row - M_DIM; isX = false; }

    const float4* s4 = reinterpret_cast<const float4*>(src + (size_t)r * D_DIM);
    float4 v = s4[lane];
    float ss = v.x * v.x + v.y * v.y + v.z * v.z + v.w * v.w;

    ushort4 b4;
    b4.x = f2bf(v.x); b4.y = f2bf(v.y); b4.z = f2bf(v.z); b4.w = f2bf(v.w);
    reinterpret_cast<ushort4*>(dst + (size_t)r * D_DIM)[lane] = b4;

    #pragma unroll
    for (int o = 1; o < 64; o <<= 1) ss += __shfl_xor(ss, o);
    if (lane == 0) {
        if (isX) sq1[r] = ss * C_EXP;
        else     sqal[r] = make_float2(ss * C_EXP, alpha[r]);
    }
}

// ---------------------------------------------------------------------------
// Fused RBF GEMM, cooperative counted-vmcnt pipeline (T3/T4):
//  - wave = 64 A-rows, full K=256 resident as MFMA frags (128 VGPR);
//    block = 4 waves = 256 rows x one 256-col slice.
//  - B staged ONCE per block per 16-col chunk (2 global_load_lds per wave)
//    into QUAD-buffered shared LDS; sqal slice staged once in prologue.
//  - per chunk: stage(i+2) -> s_waitcnt vmcnt(4) (counted, chunk i landed;
//    never 0 mid-loop) -> raw s_barrier -> ds_read/MFMA/epilogue on chunk i.
//    Quad-buffer makes one barrier/chunk race-free: writer buf (i+2)&3 vs
//    oldest concurrent reader buf (i-1)&3 differ by 3 mod 4.
//  - LDS slot swizzle s' = s ^ (col&7) on both sides (G21): 2-way max.
// MFMA frag layouts (m89/m91): A/B lane l: row/col=l&15, k=(l>>4)*8..+7
// per 32-k window; C/D: col=lane&15, row=(lane>>4)*4+reg.
// blockIdx&31 = cslice -> XCD x gets cslice%8==x: B working set 512 KB +
// A 2 MB per XCD, L2-resident.
// ---------------------------------------------------------------------------
__global__ __launch_bounds__(256, 2) void gemm_kernel(
    const unsigned short* __restrict__ Xb, const unsigned short* __restrict__ Tb,
    const float* __restrict__ sq1, const float2* __restrict__ sqal,
    float* __restrict__ part)
{
    __shared__ __align__(16) char smem[LDS_BYTES];
    const int cslice = blockIdx.x & 31;
    const int quad   = blockIdx.x >> 5;
    const int wid    = threadIdx.x >> 6;
    const int lane   = threadIdx.x & 63;
    const int l15    = lane & 15;
    const int lg     = lane >> 4;

    const int rowbase = quad * 256 + wid * 64;
    const int colbase = cslice * 256;

    // ---- A fragments: 64 rows x full K in registers (32 x dwordx4) ----
    short8 af[4][8];
    #pragma unroll
    for (int m = 0; m < 4; ++m)
        #pragma unroll
        for (int ks = 0; ks < 8; ++ks)
            af[m][ks] = *(const short8*)(Xb +
                (size_t)(rowbase + m * 16 + l15) * D_DIM + ks * 32 + lg * 8);

    float4 s1v[4];
    #pragma unroll
    for (int m = 0; m < 4; ++m)
        s1v[m] = *reinterpret_cast<const float4*>(sq1 + rowbase + m * 16 + lg * 4);
    float s1max = -1e30f;
    #pragma unroll
    for (int m = 0; m < 4; ++m)
        #pragma unroll
        for (int r = 0; r < 4; ++r) s1max = fmaxf(s1max, s1v[m][r]);

    // Pin plain global loads older than the staging stream (exact counting).
    asm volatile("s_waitcnt vmcnt(0)" ::: "memory");

    const char* TbB = (const char*)Tb;
    const char* SaB = (const char*)sqal + (size_t)colbase * 8;

    // sqal slice (2 KB): all waves issue the same 2 ops (duplicate writes of
    // identical bytes -> benign; keeps per-wave vmcnt counts uniform).
    #pragma unroll
    for (int s = 0; s < 2; ++s)
        __builtin_amdgcn_global_load_lds(
            (const __attribute__((address_space(1))) void*)(SaB + s * 1024 + lane * 16),
            (__attribute__((address_space(3))) void*)(smem + SQAL_OFF + s * 1024), 16, 0, 0);

    // stage chunk i into buffer i&3: 2 ops per wave (cooperative: 8 KB total)
    auto stage = [&](int i) {
        char* buf = smem + (i & 3) * BUFB;
        #pragma unroll
        for (int c = 0; c < 2; ++c) {
            const int j = wid * 2 + c;                    // 1 KB unit 0..7
            const int col_local = j * 2 + (lane >> 5);    // 2 cols per unit
            const size_t src = (size_t)(colbase + i * 16 + col_local) * 512
                             + (size_t)((((lane & 31) ^ (col_local & 7)) * 16));
            __builtin_amdgcn_global_load_lds(
                (const __attribute__((address_space(1))) void*)(TbB + src),
                (__attribute__((address_space(3))) void*)(buf + j * 1024), 16, 0, 0);
        }
    };

    float psum[4][4];
    #pragma unroll
    for (int m = 0; m < 4; ++m)
        #pragma unroll
        for (int r = 0; r < 4; ++r) psum[m][r] = 0.0f;

    auto compute = [&](int i) {
        const char* buf = smem + (i & 3) * BUFB;
        f32x4 acc[4];
        #pragma unroll
        for (int m = 0; m < 4; ++m) acc[m] = (f32x4)0.0f;
        #pragma unroll
        for (int ks = 0; ks < 8; ++ks) {
            const short8 bf = *(const short8*)(buf + l15 * 512 +
                (((ks * 4 + lg) ^ (l15 & 7)) * 16));
            #pragma unroll
            for (int m = 0; m < 4; ++m)
                acc[m] = __builtin_amdgcn_mfma_f32_16x16x32_bf16(
                    af[m][ks], bf, acc[m], 0, 0, 0);
        }
        const float2 sa = *(const float2*)(smem + SQAL_OFF + (i * 16 + l15) * 8);
        float amax = acc[0][0];
        #pragma unroll
        for (int m = 0; m < 4; ++m)
            #pragma unroll
            for (int r = 0; r < 4; ++r) amax = fmaxf(amax, acc[m][r]);
        const float bound = fmaf(amax, K_ACC, s1max + sa.x); // upper bound on args
        if (!__all(bound < SKIP_THR)) {
            #pragma unroll
            for (int m = 0; m < 4; ++m)
                #pragma unroll
                for (int r = 0; r < 4; ++r) {
                    const float arg = fmaf(acc[m][r], K_ACC, s1v[m][r] + sa.x);
                    psum[m][r] = fmaf(__builtin_amdgcn_exp2f(arg), sa.y, psum[m][r]);
                }
        }
    };

    stage(0);
    stage(1);
    #pragma unroll
    for (int i = 0; i < NCHUNK; ++i) {
        if (i + 2 < NCHUNK) {
            stage(i + 2);                                    // 2 ops, buf (i+2)&3
            asm volatile("s_waitcnt vmcnt(4)" ::: "memory"); // chunk i landed
        } else if (i + 1 < NCHUNK) {
            asm volatile("s_waitcnt vmcnt(2)" ::: "memory");
        } else {
            asm volatile("s_waitcnt vmcnt(0)" ::: "memory");
        }
        __builtin_amdgcn_s_barrier();   // all waves' chunk-i writes visible
        compute(i);
    }

    // ---- reduce over the 16 l15-lanes (cols) and store partials ----
    #pragma unroll
    for (int m = 0; m < 4; ++m) {
        float4 pv;
        #pragma unroll
        for (int r = 0; r < 4; ++r) {
            float p = psum[m][r];
            p += __shfl_xor(p, 1);
            p += __shfl_xor(p, 2);
            p += __shfl_xor(p, 4);
            p += __shfl_xor(p, 8);
            ((float*)&pv)[r] = p;
        }
        if (l15 == 0) // 4 lanes (lg=0..3) write 4 consecutive floats each
            *reinterpret_cast<float4*>(part + (size_t)cslice * M_DIM +
                                       rowbase + m * 16 + lg * 4) = pv;
    }
}

// ---------------------------------------------------------------------------
// reduce: out[i] = sum over 32 col-slices of part[cs][i]. 16 blocks x 256.
// ---------------------------------------------------------------------------
__global__ __launch_bounds__(256) void reduce_kernel(
    const float* __restrict__ part, float* __restrict__ out)
{
    const int gi = blockIdx.x * 256 + threadIdx.x;
    float s = 0.0f;
    #pragma unroll
    for (int b = 0; b < NSLICE; ++b) s += part[(size_t)b * M_DIM + gi];
    out[gi] = s;
}

extern "C" void kernel_launch(void* const* d_in, const int* in_sizes, int n_in,
                              void* d_out, int out_size, void* d_ws, size_t ws_size,
                              hipStream_t stream)
{
    const float* X  = (const float*)d_in[0];
    const float* T  = (const float*)d_in[1];
    const float* al = (const float*)d_in[2];
    float* out = (float*)d_out;

    char* ws = (char*)d_ws;
    unsigned short* Xb = (unsigned short*)ws;                               // 2 MiB
    unsigned short* Tb = (unsigned short*)(ws + (size_t)M_DIM * D_DIM * 2); // 4 MiB
    float* sq1  = (float*)(ws + (size_t)(M_DIM + N_DIM) * D_DIM * 2);       // 16 KiB
    float2* sqal = (float2*)(sq1 + M_DIM);                                  // 64 KiB
    float* part = (float*)(sqal + N_DIM);                                   // 512 KiB

    prep_kernel<<<(M_DIM + N_DIM) / 4, 256, 0, stream>>>(X, T, al, Xb, Tb, sq1, sqal);
    gemm_kernel<<<16 * NSLICE, 256, 0, stream>>>(Xb, Tb, sq1, sqal, part);
    reduce_kernel<<<M_DIM / 256, 256, 0, stream>>>(part, out);
}